// Round 3
// baseline (2819.699 us; speedup 1.0000x reference)
//
#include <hip/hip_runtime.h>
#include <hip/hip_bf16.h>

typedef __attribute__((ext_vector_type(8))) short short8;
typedef __attribute__((ext_vector_type(4))) float floatx4;
typedef __attribute__((ext_vector_type(4))) unsigned short us4;

__device__ __forceinline__ float bits2f(unsigned short u) {
    union { unsigned int i; float f; } v; v.i = ((unsigned int)u) << 16; return v.f;
}
__device__ __forceinline__ unsigned short f2bb(float x) {  // RNE f32->bf16 bits
    union { float f; unsigned int i; } v; v.f = x;
    unsigned int r = v.i + 0x7FFFu + ((v.i >> 16) & 1u);
    return (unsigned short)(r >> 16);
}
__device__ __forceinline__ float ldf(const void* base, long i, int fp32) {
    return fp32 ? ((const float*)base)[i] : bits2f(((const unsigned short*)base)[i]);
}
__device__ __forceinline__ short8 loadRow8(const void* base, long off, int fp32) {
    short8 r;
    if (!fp32) {
        r = *(const short8*)((const unsigned short*)base + off);
    } else {
        const float* f = (const float*)base + off;
        #pragma unroll
        for (int j = 0; j < 8; ++j) r[j] = (short)f2bb(f[j]);
    }
    return r;
}
__device__ __forceinline__ float lclamp(float z) {
    return fminf(fmaxf(z, -1e4f), 1e4f);
}

// ---------------------------------------------------------------------------
__global__ void k_probe(const unsigned short* __restrict__ Wb, int* __restrict__ flag) {
    int t = threadIdx.x;
    unsigned short u = Wb[t * 2];
    unsigned e = (u >> 7) & 0xFF;
    int in = (e >= 0x60 && e <= 0x8F) ? 1 : 0;
    unsigned long long m = __ballot(in);
    if (t == 0) flag[0] = (__popcll(m) < 32) ? 1 : 0;   // 1 => fp32
}

// ---------------------------------------------------------------------------
// K1: P[a][0:128] = atom[a]@W[0:64,:] + b ; P[a][128:256] = atom[a]@W[64:128,:]
// ---------------------------------------------------------------------------
__global__ __launch_bounds__(256) void k_atom_proj(
    const void* __restrict__ atom, const void* __restrict__ Wv,
    const void* __restrict__ bv, __hip_bfloat16* __restrict__ P,
    int N, const int* __restrict__ flagp)
{
    const int fp32 = *flagp;
    const int t = threadIdx.x;
    const int wave = t >> 6, lane = t & 63;
    const int half = wave & 1;
    const int pairInBlk = wave >> 1;
    const int n0 = lane & 15, kq = lane >> 4;

    short8 bf[8][2];
    #pragma unroll
    for (int tt = 0; tt < 8; ++tt)
        #pragma unroll
        for (int h = 0; h < 2; ++h)
            #pragma unroll
            for (int jj = 0; jj < 8; ++jj) {
                int k = half*64 + h*32 + kq*8 + jj;
                bf[tt][h][jj] = (short)f2bb(ldf(Wv, (long)k*128 + tt*16 + n0, fp32));
            }
    float bias[8];
    #pragma unroll
    for (int tt = 0; tt < 8; ++tt)
        bias[tt] = half ? 0.f : ldf(bv, tt*16 + n0, fp32);

    const long nGroups = ((long)N + 15) / 16;
    for (long g = (long)blockIdx.x*2 + pairInBlk; g < nGroups; g += (long)gridDim.x*2) {
        long a0 = g * 16;
        long am = a0 + n0;
        short8 a_lo = {}, a_hi = {};
        if (am < N) {
            a_lo = loadRow8(atom, am*64 + kq*8, fp32);
            a_hi = loadRow8(atom, am*64 + 32 + kq*8, fp32);
        }
        #pragma unroll
        for (int tt = 0; tt < 8; ++tt) {
            floatx4 c = {0.f, 0.f, 0.f, 0.f};
            c = __builtin_amdgcn_mfma_f32_16x16x32_bf16(a_lo, bf[tt][0], c, 0, 0, 0);
            c = __builtin_amdgcn_mfma_f32_16x16x32_bf16(a_hi, bf[tt][1], c, 0, 0, 0);
            #pragma unroll
            for (int r = 0; r < 4; ++r) {
                long a = a0 + kq*4 + r;
                if (a < N)
                    P[a*256 + half*128 + tt*16 + n0] =
                        __float2bfloat16(lclamp(c[r] + bias[tt]));
            }
        }
    }
}

// ---------------------------------------------------------------------------
// Phase A (transposed): z^T tile. A = W3^T (features m), B = nbr rows (edge cols).
// C/D: col = edge (lane&15), row = feature (kq*4+r) -> vectorized 8B P gathers.
// Accumulates BN1 sum/sumsq; stores z bf16 [E][128].
// ---------------------------------------------------------------------------
__global__ __launch_bounds__(256) void k_edge_gemm(
    const void* __restrict__ nbr,
    const int* __restrict__ esrc,
    const int* __restrict__ edst,
    const void* __restrict__ Wv,
    const unsigned short* __restrict__ Pb,   // bf16 bits [N][256]
    float* __restrict__ stats,               // [256]
    unsigned short* __restrict__ z,          // bf16 bits [E][128]
    long E, const int* __restrict__ flagp)
{
    __shared__ float s_sum[128], s_ss[128];
    const int fp32 = *flagp;
    const int t = threadIdx.x;
    const int wave = t >> 6, lane = t & 63;
    const int n0 = lane & 15, kq = lane >> 4;

    if (t < 128) { s_sum[t] = 0.f; s_ss[t] = 0.f; }
    __syncthreads();

    // A = W3^T fragments: af[tt][h][jj] = W[128 + h*32 + kq*8 + jj][tt*16 + n0]
    short8 af[8][2];
    #pragma unroll
    for (int tt = 0; tt < 8; ++tt)
        #pragma unroll
        for (int h = 0; h < 2; ++h)
            #pragma unroll
            for (int jj = 0; jj < 8; ++jj) {
                int k = 128 + h*32 + kq*8 + jj;
                af[tt][h][jj] = (short)f2bb(ldf(Wv, (long)k*128 + tt*16 + n0, fp32));
            }

    float lsum[8][4], lss[8][4];
    #pragma unroll
    for (int tt = 0; tt < 8; ++tt)
        #pragma unroll
        for (int r = 0; r < 4; ++r) { lsum[tt][r] = 0.f; lss[tt][r] = 0.f; }

    const long nG = (E + 15) / 16;
    for (long g = (long)blockIdx.x*4 + wave; g < nG; g += (long)gridDim.x*4) {
        long e0 = g * 16;
        long e  = e0 + n0;                 // this lane's edge (column)
        bool ev = (e < E);
        short8 b_lo = {}, b_hi = {};
        int sE = 0, dE = 0;
        if (ev) {
            b_lo = loadRow8(nbr, e*64 + kq*8, fp32);
            b_hi = loadRow8(nbr, e*64 + 32 + kq*8, fp32);
            sE = esrc[e]; dE = edst[e];
        }
        // vectorized P gathers: 8B each, 4 contiguous features (kq*4 + 0..3)
        us4 p1[8], p2[8];
        #pragma unroll
        for (int tt = 0; tt < 8; ++tt) {
            p1[tt] = *(const us4*)(Pb + (long)sE*256 + tt*16 + kq*4);
            p2[tt] = *(const us4*)(Pb + (long)dE*256 + 128 + tt*16 + kq*4);
        }
        #pragma unroll
        for (int tt = 0; tt < 8; ++tt) {
            floatx4 c = {0.f, 0.f, 0.f, 0.f};
            c = __builtin_amdgcn_mfma_f32_16x16x32_bf16(af[tt][0], b_lo, c, 0, 0, 0);
            c = __builtin_amdgcn_mfma_f32_16x16x32_bf16(af[tt][1], b_hi, c, 0, 0, 0);
            us4 zo;
            #pragma unroll
            for (int r = 0; r < 4; ++r) {
                float zv = lclamp(c[r] + bits2f(p1[tt][r]) + bits2f(p2[tt][r]));
                zo[r] = f2bb(zv);
                if (ev) { lsum[tt][r] += zv; lss[tt][r] += zv*zv; }
            }
            if (ev) *(us4*)(z + e*128 + tt*16 + kq*4) = zo;
        }
    }
    // fold per-lane stats into LDS, then global
    #pragma unroll
    for (int tt = 0; tt < 8; ++tt)
        #pragma unroll
        for (int r = 0; r < 4; ++r) {
            int n = tt*16 + kq*4 + r;
            atomicAdd(&s_sum[n], lsum[tt][r]);
            atomicAdd(&s_ss[n],  lss[tt][r]);
        }
    __syncthreads();
    if (t < 128) {
        atomicAdd(&stats[t], s_sum[t]);
        atomicAdd(&stats[128 + t], s_ss[t]);
    }
}

// ---------------------------------------------------------------------------
// Phase B: streaming gate + scatter. 4 edges/wave/iter; lane covers 8 features.
// ---------------------------------------------------------------------------
__global__ __launch_bounds__(256) void k_apply(
    const unsigned short* __restrict__ z,    // bf16 bits [E][128]
    const int* __restrict__ edst,
    const float* __restrict__ coef,          // scale[128], shift[128]
    float* __restrict__ au, long E)
{
    const int t = threadIdx.x;
    const int wave = t >> 6, lane = t & 63;
    const int esub = lane >> 4, fg = lane & 15;

    float sc[8], sh[8];
    #pragma unroll
    for (int j = 0; j < 8; ++j) {
        sc[j] = coef[fg*8 + j];
        sh[j] = coef[128 + fg*8 + j];
    }

    const long nG = (E + 3) / 4;
    for (long g = (long)blockIdx.x*4 + wave; g < nG; g += (long)gridDim.x*4) {
        long e = g*4 + esub;
        bool ev = (e < E);
        short8 zr = {};
        int dE = 0;
        if (ev) {
            zr = *(const short8*)((const short*)z + e*128 + fg*8);
            dE = edst[e];
        }
        float v[8];
        #pragma unroll
        for (int j = 0; j < 8; ++j)
            v[j] = bits2f((unsigned short)zr[j]) * sc[j] + sh[j];
        float p[8];
        #pragma unroll
        for (int j = 0; j < 8; ++j) p[j] = __shfl_xor(v[j], 8);
        if (ev) {
            if (fg < 8) {
                #pragma unroll
                for (int j = 0; j < 4; ++j) {
                    float sig = 1.f / (1.f + __expf(-v[j]));
                    float sp  = fmaxf(p[j], 0.f) + log1pf(__expf(-fabsf(p[j])));
                    atomicAdd(au + (long)dE*64 + fg*8 + j, sig * sp);
                }
            } else {
                #pragma unroll
                for (int j = 4; j < 8; ++j) {
                    float sig = 1.f / (1.f + __expf(-p[j]));
                    float sp  = fmaxf(v[j], 0.f) + log1pf(__expf(-fabsf(v[j])));
                    atomicAdd(au + (long)dE*64 + (fg - 8)*8 + j, sig * sp);
                }
            }
        }
    }
}

// ---------------------------------------------------------------------------
// Fallback (round-2 verified): two-pass gather k_edge, used only if ws too small
// ---------------------------------------------------------------------------
template<int PHASE>
__global__ __launch_bounds__(256) void k_edge(
    const void* __restrict__ nbr, const int* __restrict__ esrc,
    const int* __restrict__ edst, const void* __restrict__ Wv,
    const unsigned short* __restrict__ Pb, const float* __restrict__ coef,
    float* __restrict__ outAcc, long E, const int* __restrict__ flagp)
{
    __shared__ float s_sum[128], s_ss[128];
    const int fp32 = *flagp;
    const int t = threadIdx.x;
    const int wave = t >> 6, lane = t & 63;
    const int n0 = lane & 15, kq = lane >> 4;

    short8 bf[8][2];
    #pragma unroll
    for (int tt = 0; tt < 8; ++tt)
        #pragma unroll
        for (int h = 0; h < 2; ++h)
            #pragma unroll
            for (int jj = 0; jj < 8; ++jj) {
                int k = 128 + h*32 + kq*8 + jj;
                bf[tt][h][jj] = (short)f2bb(ldf(Wv, (long)k*128 + tt*16 + n0, fp32));
            }
    float sc[8], sh[8];
    if (PHASE == 1) {
        #pragma unroll
        for (int tt = 0; tt < 8; ++tt) {
            sc[tt] = coef[tt*16 + n0];
            sh[tt] = coef[128 + tt*16 + n0];
        }
    }
    float lsum[8], lss[8];
    if (PHASE == 0) {
        if (t < 128) { s_sum[t] = 0.f; s_ss[t] = 0.f; }
        #pragma unroll
        for (int tt = 0; tt < 8; ++tt) { lsum[tt] = 0.f; lss[tt] = 0.f; }
        __syncthreads();
    }
    const long nGroups = (E + 15) / 16;
    for (long g = (long)blockIdx.x*4 + wave; g < nGroups; g += (long)gridDim.x*4) {
        long e0 = g * 16;
        long ea = e0 + n0;
        short8 a_lo = {}, a_hi = {};
        if (ea < E) {
            a_lo = loadRow8(nbr, ea*64 + kq*8, fp32);
            a_hi = loadRow8(nbr, ea*64 + 32 + kq*8, fp32);
        }
        floatx4 acc[8];
        #pragma unroll
        for (int tt = 0; tt < 8; ++tt) {
            floatx4 c = {0.f, 0.f, 0.f, 0.f};
            c = __builtin_amdgcn_mfma_f32_16x16x32_bf16(a_lo, bf[tt][0], c, 0, 0, 0);
            c = __builtin_amdgcn_mfma_f32_16x16x32_bf16(a_hi, bf[tt][1], c, 0, 0, 0);
            acc[tt] = c;
        }
        int sE[4], dE[4];
        #pragma unroll
        for (int r = 0; r < 4; ++r) {
            long er = e0 + kq*4 + r;
            sE[r] = (er < E) ? esrc[er] : 0;
            dE[r] = (er < E) ? edst[er] : 0;
        }
        if (PHASE == 0) {
            #pragma unroll
            for (int tt = 0; tt < 8; ++tt) {
                int n = tt*16 + n0;
                #pragma unroll
                for (int r = 0; r < 4; ++r) {
                    long er = e0 + kq*4 + r;
                    if (er < E) {
                        float zv = lclamp(acc[tt][r]
                                + bits2f(Pb[(long)sE[r]*256 + n])
                                + bits2f(Pb[(long)dE[r]*256 + 128 + n]));
                        lsum[tt] += zv; lss[tt] += zv*zv;
                    }
                }
            }
        } else {
            float zh[8][4];
            #pragma unroll
            for (int tt = 0; tt < 8; ++tt) {
                int n = tt*16 + n0;
                #pragma unroll
                for (int r = 0; r < 4; ++r) {
                    float zv = lclamp(acc[tt][r]
                            + bits2f(Pb[(long)sE[r]*256 + n])
                            + bits2f(Pb[(long)dE[r]*256 + 128 + n]));
                    zh[tt][r] = zv * sc[tt] + sh[tt];
                }
            }
            #pragma unroll
            for (int tt = 0; tt < 4; ++tt)
                #pragma unroll
                for (int r = 0; r < 4; ++r) {
                    long er = e0 + kq*4 + r;
                    if (er < E) {
                        float f = zh[tt][r], c = zh[tt+4][r];
                        float sig = 1.f / (1.f + __expf(-f));
                        float sp  = fmaxf(c, 0.f) + log1pf(__expf(-fabsf(c)));
                        atomicAdd(outAcc + (long)dE[r]*64 + tt*16 + n0, sig * sp);
                    }
                }
        }
    }
    if (PHASE == 0) {
        #pragma unroll
        for (int tt = 0; tt < 8; ++tt) {
            atomicAdd(&s_sum[tt*16 + n0], lsum[tt]);
            atomicAdd(&s_ss[tt*16 + n0], lss[tt]);
        }
        __syncthreads();
        if (t < 128) {
            atomicAdd(&outAcc[t], s_sum[t]);
            atomicAdd(&outAcc[128 + t], s_ss[t]);
        }
    }
}

// ---------------------------------------------------------------------------
__global__ void k_fin1(const float* __restrict__ stats,
                       const void* __restrict__ gamma, const void* __restrict__ beta,
                       float* __restrict__ coef, float invE, const int* __restrict__ flagp)
{
    const int fp32 = *flagp;
    int t = threadIdx.x;  // 128
    float mean = stats[t] * invE;
    float var  = fmaxf(stats[128 + t] * invE - mean * mean, 0.f);
    float sc = ldf(gamma, t, fp32) * rsqrtf(var + 1e-5f);
    coef[t] = sc;
    coef[128 + t] = ldf(beta, t, fp32) - mean * sc;
}

__global__ void k_au_stats(const float* __restrict__ au, float* __restrict__ stats, int N)
{
    __shared__ float s_red[256];
    int t = threadIdx.x;
    int j = t & 63, r = t >> 6;
    float lsum = 0.f, lss = 0.f;
    for (int base = blockIdx.x * 4; base < N; base += gridDim.x * 4) {
        int a = base + r;
        if (a < N) { float v = au[(long)a*64 + j]; lsum += v; lss += v*v; }
    }
    s_red[t] = lsum; __syncthreads();
    if (t < 64) atomicAdd(&stats[j], s_red[j] + s_red[j+64] + s_red[j+128] + s_red[j+192]);
    __syncthreads();
    s_red[t] = lss; __syncthreads();
    if (t < 64) atomicAdd(&stats[64+j], s_red[j] + s_red[j+64] + s_red[j+128] + s_red[j+192]);
}

__global__ void k_fin2(const float* __restrict__ stats,
                       const void* __restrict__ gamma, const void* __restrict__ beta,
                       float* __restrict__ coef, float invN, const int* __restrict__ flagp)
{
    const int fp32 = *flagp;
    int t = threadIdx.x;  // 64
    float mean = stats[t] * invN;
    float var  = fmaxf(stats[64 + t] * invN - mean * mean, 0.f);
    float sc = ldf(gamma, t, fp32) * rsqrtf(var + 1e-5f);
    coef[t] = sc;
    coef[64 + t] = ldf(beta, t, fp32) - mean * sc;
}

__global__ void k_out(const void* __restrict__ atom, const float* __restrict__ au,
                      const float* __restrict__ coef2, void* __restrict__ out,
                      long total, const int* __restrict__ flagp)
{
    const int fp32 = *flagp;
    long i = (long)blockIdx.x * blockDim.x + threadIdx.x;
    if (i >= total) return;
    int j = (int)(i & 63);
    float x = lclamp(ldf(atom, i, fp32) + au[i] * coef2[j] + coef2[64 + j]);
    float sp = fmaxf(x, 0.f) + log1pf(__expf(-fabsf(x)));
    if (fp32) ((float*)out)[i] = sp;
    else      ((__hip_bfloat16*)out)[i] = __float2bfloat16(sp);
}

// ---------------------------------------------------------------------------
extern "C" void kernel_launch(void* const* d_in, const int* in_sizes, int n_in,
                              void* d_out, int out_size, void* d_ws, size_t ws_size,
                              hipStream_t stream)
{
    const void* atom = d_in[0];
    const void* nbr  = d_in[1];
    const int* esrc = (const int*)d_in[2];
    const int* edst = (const int*)d_in[3];
    const void* Wv  = d_in[4];
    const void* bv  = d_in[5];
    const void* g1  = d_in[6];
    const void* be1 = d_in[7];
    const void* g2  = d_in[8];
    const void* be2 = d_in[9];

    const int  N = in_sizes[0] / 64;
    const long E = (long)in_sizes[1] / 64;

    char* w = (char*)d_ws;
    __hip_bfloat16* P = (__hip_bfloat16*)w;  w += (size_t)N * 256 * sizeof(__hip_bfloat16);
    float* au     = (float*)w;               w += (size_t)N * 64 * sizeof(float);
    float* stats1 = (float*)w;               w += 256 * sizeof(float);
    float* stats2 = (float*)w;               w += 128 * sizeof(float);
    float* coef1  = (float*)w;               w += 256 * sizeof(float);
    float* coef2  = (float*)w;               w += 128 * sizeof(float);
    int* flagp    = (int*)w;                 w += 256;  // keep z 256B-aligned
    unsigned short* z = (unsigned short*)w;

    const size_t fixed = (size_t)(w - (char*)d_ws);
    const bool bigws = ws_size >= fixed + (size_t)E * 128 * sizeof(unsigned short);

    hipMemsetAsync(au, 0, (size_t)N * 64 * sizeof(float), stream);
    hipMemsetAsync(stats1, 0, 384 * sizeof(float), stream);

    k_probe<<<1, 64, 0, stream>>>((const unsigned short*)Wv, flagp);
    k_atom_proj<<<1024, 256, 0, stream>>>(atom, Wv, bv, P, N, flagp);

    if (bigws) {
        k_edge_gemm<<<2048, 256, 0, stream>>>(nbr, esrc, edst, Wv,
                                              (const unsigned short*)P, stats1, z, E, flagp);
        k_fin1<<<1, 128, 0, stream>>>(stats1, g1, be1, coef1, 1.0f / (float)E, flagp);
        k_apply<<<2048, 256, 0, stream>>>(z, edst, coef1, au, E);
    } else {
        k_edge<0><<<2048, 256, 0, stream>>>(nbr, esrc, edst, Wv,
                                            (const unsigned short*)P, nullptr, stats1, E, flagp);
        k_fin1<<<1, 128, 0, stream>>>(stats1, g1, be1, coef1, 1.0f / (float)E, flagp);
        k_edge<1><<<2048, 256, 0, stream>>>(nbr, esrc, edst, Wv,
                                            (const unsigned short*)P, coef1, au, E, flagp);
    }
    k_au_stats<<<1024, 256, 0, stream>>>(au, stats2, N);
    k_fin2<<<1, 64, 0, stream>>>(stats2, g2, be2, coef2, 1.0f / (float)N, flagp);
    long total = (long)N * 64;
    k_out<<<(int)((total + 255) / 256), 256, 0, stream>>>(atom, au, coef2,
                                                          d_out, total, flagp);
}